// Round 4
// baseline (288.488 us; speedup 1.0000x reference)
//
#include <hip/hip_runtime.h>
#include <hip/hip_bf16.h>

// Problem constants
#define NROWS   200000
#define TILE    32                  // rows (n) per block
#define NBLOCKS (NROWS / TILE)      // 6250, exact

typedef __attribute__((ext_vector_type(4))) float f32x4;
typedef __attribute__((ext_vector_type(8))) short bf16x8;

// fp32 pair -> packed bf16x2 (RNE) via v_cvt_pk_bf16_f32 (compiler-lowered)
__device__ __forceinline__ unsigned pk2(float lo, float hi) {
  float2 f{lo, hi};
  __hip_bfloat162 h = __float22bfloat162_rn(f);
  unsigned u;
  __builtin_memcpy(&u, &h, 4);
  return u;
}
// scalar fp32 -> bf16 bits (RNE) — only used in weight prep (runs once)
__device__ __forceinline__ unsigned short f2bf(float f) {
  unsigned b = __float_as_uint(f);
  b += 0x7fffu + ((b >> 16) & 1u);
  return (unsigned short)(b >> 16);
}
__device__ __forceinline__ float bflo(unsigned pk) { return __uint_as_float(pk << 16); }
__device__ __forceinline__ float bfhi(unsigned pk) { return __uint_as_float(pk & 0xffff0000u); }
__device__ __forceinline__ f32x4 mfma16(bf16x8 a, bf16x8 b, f32x4 c) {
  return __builtin_amdgcn_mfma_f32_16x16x32_bf16(a, b, c, 0, 0, 0);
}
__device__ __forceinline__ float fast_tanh(float x) {
  float e = __expf(2.0f * x);
  return 1.0f - __fdividef(2.0f, e + 1.0f);
}
// LDS XOR swizzle on byte offsets (uniform 256B row pitch, row = byte>>8):
// flips bits 4..6 with row&7 -> strided row-column reads spread across 8
// 16B slots (<=2-way bank aliasing = free, m136). Pure function of the
// offset -> writes and reads always consistent. Preserves 16B alignment.
__device__ __forceinline__ int SW(int b) { return b ^ (((b >> 8) & 7) << 4); }

// ---------------------------------------------------------------------------
// Weight prep: W[K][Nout] fp32 -> bf16 MFMA-B fragments with INTERLEAVED
// column mapping: fragment (kt,nt), lane l, elem i <-
//     W[kt*32 + 8*(l>>4) + i][(nt>>1)*32 + 2*(l&15) + (nt&1)]
// Waves own tile pairs (nt=2w, 2w+1), so a lane's two D-columns are the
// ADJACENT features 32w+2*lr and 32w+2*lr+1 -> packed b32 LDS writes and
// float2 global stores downstream.
// ---------------------------------------------------------------------------
__global__ void prep_weights(const float* __restrict__ Wp,
                             const float* __restrict__ W1,
                             const float* __restrict__ W2,
                             unsigned short* __restrict__ wpf,
                             unsigned short* __restrict__ w1f,
                             unsigned short* __restrict__ w2f) {
  int t = blockIdx.x * 256 + threadIdx.x;   // 72*256 = 18432 = 288*64
  int q = t >> 6, l = t & 63;
  const float* W; unsigned short* dst; int NT, Nout, qb;
  if (q < 32)       { W = Wp; dst = wpf; NT = 8;  Nout = 128; qb = q; }
  else if (q < 160) { W = W1; dst = w1f; NT = 32; Nout = 512; qb = q - 32; }
  else              { W = W2; dst = w2f; NT = 8;  Nout = 128; qb = q - 160; }
  int kt = qb / NT, nt = qb % NT;
  int row0 = kt * 32 + 8 * (l >> 4);
  int col  = (nt >> 1) * 32 + 2 * (l & 15) + (nt & 1);   // interleaved
  unsigned short v[8];
#pragma unroll
  for (int i = 0; i < 8; ++i) v[i] = f2bf(W[(row0 + i) * Nout + col]);
  uint4 pack;
  pack.x = (unsigned)v[0] | ((unsigned)v[1] << 16);
  pack.y = (unsigned)v[2] | ((unsigned)v[3] << 16);
  pack.z = (unsigned)v[4] | ((unsigned)v[5] << 16);
  pack.w = (unsigned)v[6] | ((unsigned)v[7] << 16);
  *(uint4*)(dst + (size_t)(qb * 64 + l) * 8) = pack;
}

// ---------------------------------------------------------------------------
// Fused kernel. 32 rows / 256 threads (4 waves). LDS = 32768 B.
// LDS map (256B pitch, SW-swizzled):
//   [0,24576): x bf16 [96 rows'=3n+d][128]    (dead after GEMM1)
//     overlay: h1 buf0 @0 (8KB) | h1 buf1 @8192 (8KB) | h2 @16384 (8KB)
//   [24576,32768): c bf16 [32][128]
// 7 barriers; h1 double-buffered. launch_bounds(256,3): reg budget ~170
// total (arch+AGPR) -> 3 waves/SIMD without spilling (R2 showed 128 spills,
// R3 showed 256-budget sprawls to 2 waves/SIMD).
// ---------------------------------------------------------------------------
__global__ __launch_bounds__(256, 3) void fused_kernel(
    const float* __restrict__ x,
    const float* __restrict__ b1,
    const float* __restrict__ b2,
    const unsigned short* __restrict__ wpf,
    const unsigned short* __restrict__ w1f,
    const unsigned short* __restrict__ w2f,
    float* __restrict__ out) {
  __shared__ __align__(16) char smem[32768];
  const int t = threadIdx.x;
  const int l = t & 63;
  const int w = t >> 6;        // wave id (uniform per wave)
  const int lr = l & 15;
  const int lq = l >> 4;
  const long n0 = (long)blockIdx.x * TILE;

  // ---- P0: stage x -> bf16 LDS; c = sum_d x^2 in fp32 from un-rounded x.
  {
    float4 v[4][3];
#pragma unroll
    for (int k = 0; k < 4; ++k) {
      int p = t + k * 256, r = p >> 5, f = (p & 31) * 4;
      const float* xp = x + (n0 + r) * 384 + f;
      v[k][0] = *(const float4*)(xp);
      v[k][1] = *(const float4*)(xp + 128);
      v[k][2] = *(const float4*)(xp + 256);
    }
#pragma unroll
    for (int k = 0; k < 4; ++k) {
      int p = t + k * 256, r = p >> 5, f = (p & 31) * 4;
      float4 a = v[k][0], b = v[k][1], c = v[k][2];
      uint2 s0 = { pk2(a.x, a.y), pk2(a.z, a.w) };
      uint2 s1 = { pk2(b.x, b.y), pk2(b.z, b.w) };
      uint2 s2 = { pk2(c.x, c.y), pk2(c.z, c.w) };
      uint2 sc = { pk2(a.x*a.x + b.x*b.x + c.x*c.x,
                       a.y*a.y + b.y*b.y + c.y*c.y),
                   pk2(a.z*a.z + b.z*b.z + c.z*c.z,
                       a.w*a.w + b.w*b.w + c.w*c.w) };
      *(uint2*)(smem + SW((3 * r + 0) * 256 + f * 2)) = s0;
      *(uint2*)(smem + SW((3 * r + 1) * 256 + f * 2)) = s1;
      *(uint2*)(smem + SW((3 * r + 2) * 256 + f * 2)) = s2;
      *(uint2*)(smem + SW(24576 + r * 256 + f * 2))   = sc;
    }
  }
  __syncthreads();   // (1) x + c visible

  // ---- GEMM1: linx[r'][g], 96x128. Wave w owns interleaved cols
  // {32w+2*lr, 32w+2*lr+1} via tiles {2w,2w+1}. Packed to bf16 pairs.
  unsigned lx[6][4];
  {
    f32x4 acc1[6][2] = {};
#pragma unroll
    for (int kt = 0; kt < 4; ++kt) {
      bf16x8 a[6];
#pragma unroll
      for (int mt = 0; mt < 6; ++mt)
        a[mt] = *(const bf16x8*)(smem + SW((mt * 16 + lr) * 256 + kt * 64 + lq * 16));
#pragma unroll
      for (int jj = 0; jj < 2; ++jj) {
        bf16x8 b = *(const bf16x8*)(wpf + (size_t)((kt * 8 + 2 * w + jj) * 64 + l) * 8);
#pragma unroll
        for (int mt = 0; mt < 6; ++mt) acc1[mt][jj] = mfma16(a[mt], b, acc1[mt][jj]);
      }
    }
#pragma unroll
    for (int mt = 0; mt < 6; ++mt)
#pragma unroll
      for (int reg = 0; reg < 4; ++reg)
        lx[mt][reg] = pk2(acc1[mt][0][reg], acc1[mt][1][reg]);
  }

  // ---- MLP, K-chunked (128 mids/chunk), h1 double-buffered in dead-x.
  f32x4 acc3[2][2] = {};
#pragma unroll
  for (int ch = 0; ch < 4; ++ch) {
    // GEMM2 chunk: reads c only (no LDS hazard yet)
    f32x4 acc2[2][2] = {};
#pragma unroll
    for (int kt = 0; kt < 4; ++kt) {
      bf16x8 a2[2];
#pragma unroll
      for (int mt = 0; mt < 2; ++mt)
        a2[mt] = *(const bf16x8*)(smem + SW(24576 + (mt * 16 + lr) * 256 + kt * 64 + lq * 16));
#pragma unroll
      for (int jj = 0; jj < 2; ++jj) {
        bf16x8 b = *(const bf16x8*)(w1f + (size_t)((kt * 32 + ch * 8 + 2 * w + jj) * 64 + l) * 8);
#pragma unroll
        for (int mt = 0; mt < 2; ++mt) acc2[mt][jj] = mfma16(a2[mt], b, acc2[mt][jj]);
      }
    }
    if (ch == 0) __syncthreads();   // (2) GEMM1's x reads done before buf0 write
    // epilogue: bias + tanh, packed pair -> one ds_write_b32 per (mt,reg)
    const int bufb = (ch & 1) * 8192;
    float2 b1v = *(const float2*)(b1 + ch * 128 + w * 32 + 2 * lr);
#pragma unroll
    for (int mt = 0; mt < 2; ++mt)
#pragma unroll
      for (int reg = 0; reg < 4; ++reg) {
        int row = mt * 16 + 4 * lq + reg;
        unsigned pk = pk2(fast_tanh(acc2[mt][0][reg] + b1v.x),
                          fast_tanh(acc2[mt][1][reg] + b1v.y));
        *(unsigned*)(smem + SW(bufb + row * 256 + w * 64 + 4 * lr)) = pk;
      }
    __syncthreads();   // (3..6) h1 chunk visible
    // GEMM3 partial: acc3 += h1c @ W2[K-slice,:]
#pragma unroll
    for (int kt = 0; kt < 4; ++kt) {
      bf16x8 a3[2];
#pragma unroll
      for (int mt = 0; mt < 2; ++mt)
        a3[mt] = *(const bf16x8*)(smem + SW(bufb + (mt * 16 + lr) * 256 + kt * 64 + lq * 16));
#pragma unroll
      for (int jj = 0; jj < 2; ++jj) {
        bf16x8 b = *(const bf16x8*)(w2f + (size_t)(((ch * 4 + kt) * 8 + 2 * w + jj) * 64 + l) * 8);
#pragma unroll
        for (int mt = 0; mt < 2; ++mt) acc3[mt][jj] = mfma16(a3[mt], b, acc3[mt][jj]);
      }
    }
  }

  // ---- h2 = acc3 + b2 -> bf16 pairs @16384 (x rows 64..95: dead, unused)
  {
    float2 b2v = *(const float2*)(b2 + w * 32 + 2 * lr);
#pragma unroll
    for (int mt = 0; mt < 2; ++mt)
#pragma unroll
      for (int reg = 0; reg < 4; ++reg) {
        int row = mt * 16 + 4 * lq + reg;
        *(unsigned*)(smem + SW(16384 + row * 256 + w * 64 + 4 * lr)) =
            pk2(acc3[mt][0][reg] + b2v.x, acc3[mt][1][reg] + b2v.y);
      }
  }
  __syncthreads();   // (7) h2 visible

  // ---- Final: out[n,d,g] = linx * h2, float2 stores (128B segments/quad)
#pragma unroll
  for (int mt = 0; mt < 6; ++mt)
#pragma unroll
    for (int reg = 0; reg < 4; ++reg) {
      int rp = mt * 16 + 4 * lq + reg;
      int n = rp / 3;   // magic-mul
      unsigned hp = *(const unsigned*)(smem + SW(16384 + n * 256 + w * 64 + 4 * lr));
      unsigned pk = lx[mt][reg];
      float2 o = { bflo(pk) * bflo(hp), bfhi(pk) * bfhi(hp) };
      *(float2*)(out + n0 * 384 + (long)rp * 128 + w * 32 + 2 * lr) = o;
    }
}

extern "C" void kernel_launch(void* const* d_in, const int* in_sizes, int n_in,
                              void* d_out, int out_size, void* d_ws, size_t ws_size,
                              hipStream_t stream) {
  const float* x  = (const float*)d_in[0];
  const float* Wp = (const float*)d_in[1];
  const float* W1 = (const float*)d_in[2];
  const float* b1 = (const float*)d_in[3];
  const float* W2 = (const float*)d_in[4];
  const float* b2 = (const float*)d_in[5];
  float* out = (float*)d_out;

  // ws layout: W1f [128KB] | W2f [128KB] | Wpf [32KB]
  if (ws_size < 294912) return;
  unsigned short* w1f = (unsigned short*)d_ws;
  unsigned short* w2f = (unsigned short*)((char*)d_ws + 131072);
  unsigned short* wpf = (unsigned short*)((char*)d_ws + 262144);

  prep_weights<<<72, 256, 0, stream>>>(Wp, W1, W2, wpf, w1f, w2f);
  fused_kernel<<<NBLOCKS, 256, 0, stream>>>(x, b1, b2, wpf, w1f, w2f, out);
}

// Round 5
// 286.985 us; speedup vs baseline: 1.0052x; 1.0052x over previous
//
#include <hip/hip_runtime.h>
#include <hip/hip_bf16.h>

// Problem constants
#define NROWS   200000
#define TILE    32                  // rows (n) per block
#define NBLOCKS (NROWS / TILE)      // 6250, exact

typedef __attribute__((ext_vector_type(4))) float f32x4;
typedef __attribute__((ext_vector_type(8))) short bf16x8;

// fp32 pair -> packed bf16x2 (RNE) via v_cvt_pk_bf16_f32 (compiler-lowered)
__device__ __forceinline__ unsigned pk2(float lo, float hi) {
  float2 f{lo, hi};
  __hip_bfloat162 h = __float22bfloat162_rn(f);
  unsigned u;
  __builtin_memcpy(&u, &h, 4);
  return u;
}
// scalar fp32 -> bf16 bits (RNE) — weight prep only (runs once)
__device__ __forceinline__ unsigned short f2bf(float f) {
  unsigned b = __float_as_uint(f);
  b += 0x7fffu + ((b >> 16) & 1u);
  return (unsigned short)(b >> 16);
}
__device__ __forceinline__ float bflo(unsigned pk) { return __uint_as_float(pk << 16); }
__device__ __forceinline__ float bfhi(unsigned pk) { return __uint_as_float(pk & 0xffff0000u); }
__device__ __forceinline__ f32x4 mfma16(bf16x8 a, bf16x8 b, f32x4 c) {
  return __builtin_amdgcn_mfma_f32_16x16x32_bf16(a, b, c, 0, 0, 0);
}
__device__ __forceinline__ float fast_tanh(float x) {
  float e = __expf(2.0f * x);
  return 1.0f - __fdividef(2.0f, e + 1.0f);
}
// cvt 8 fp32 (two float4) -> bf16x8 via 4 packed converts
__device__ __forceinline__ bf16x8 cvt8(float4 a, float4 b) {
  union { unsigned u[4]; bf16x8 v; } c;
  c.u[0] = pk2(a.x, a.y); c.u[1] = pk2(a.z, a.w);
  c.u[2] = pk2(b.x, b.y); c.u[3] = pk2(b.z, b.w);
  return c.v;
}
// LDS XOR swizzle on byte offsets (uniform 256B row pitch, row = byte>>8):
// flips bits 4..6 with row&7; pure function of offset -> consistent; keeps
// 16B alignment. <=2-way bank aliasing on row-column b128 reads (free, m136).
__device__ __forceinline__ int SW(int b) { return b ^ (((b >> 8) & 7) << 4); }

// ---------------------------------------------------------------------------
// Weight prep: W[K][Nout] fp32 -> bf16 MFMA-B fragments with INTERLEAVED
// column mapping: fragment (kt,nt), lane l, elem i <-
//     W[kt*32 + 8*(l>>4) + i][(nt>>1)*32 + 2*(l&15) + (nt&1)]
// Wave w owns tiles {2w,2w+1} -> its lane's two D-cols are adjacent features
// 32w+2*lr{,+1} -> packed b32 LDS writes / float2 global stores downstream.
// ---------------------------------------------------------------------------
__global__ void prep_weights(const float* __restrict__ Wp,
                             const float* __restrict__ W1,
                             const float* __restrict__ W2,
                             unsigned short* __restrict__ wpf,
                             unsigned short* __restrict__ w1f,
                             unsigned short* __restrict__ w2f) {
  int t = blockIdx.x * 256 + threadIdx.x;   // 72*256 = 18432 = 288*64
  int q = t >> 6, l = t & 63;
  const float* W; unsigned short* dst; int NT, Nout, qb;
  if (q < 32)       { W = Wp; dst = wpf; NT = 8;  Nout = 128; qb = q; }
  else if (q < 160) { W = W1; dst = w1f; NT = 32; Nout = 512; qb = q - 32; }
  else              { W = W2; dst = w2f; NT = 8;  Nout = 128; qb = q - 160; }
  int kt = qb / NT, nt = qb % NT;
  int row0 = kt * 32 + 8 * (l >> 4);
  int col  = (nt >> 1) * 32 + 2 * (l & 15) + (nt & 1);   // interleaved
  unsigned short v[8];
#pragma unroll
  for (int i = 0; i < 8; ++i) v[i] = f2bf(W[(row0 + i) * Nout + col]);
  uint4 pack;
  pack.x = (unsigned)v[0] | ((unsigned)v[1] << 16);
  pack.y = (unsigned)v[2] | ((unsigned)v[3] << 16);
  pack.z = (unsigned)v[4] | ((unsigned)v[5] << 16);
  pack.w = (unsigned)v[6] | ((unsigned)v[7] << 16);
  *(uint4*)(dst + (size_t)(qb * 64 + l) * 8) = pack;
}

// ---------------------------------------------------------------------------
// Fused kernel, restructured (R5): GEMM1 LAST with fused multiply-store and
// direct global A-fragment loads (x re-read hits L3). No persistent lx.
// LDS = 24576 B:  c bf16[32][128] @0 | h1 buf0 @8192 | h1 buf1 @16384
//                 (h2 reuses buf0 after the last GEMM3 chunk)
// Phase order: P0 (c only) | MLP chunks (dbuf h1) | h2->LDS | GEMM1*h2->out.
// 6 barriers. Peak regs ~90-100 -> launch_bounds(256,4) without spilling.
// ---------------------------------------------------------------------------
__global__ __launch_bounds__(256, 4) void fused_kernel(
    const float* __restrict__ x,
    const float* __restrict__ b1,
    const float* __restrict__ b2,
    const unsigned short* __restrict__ wpf,
    const unsigned short* __restrict__ w1f,
    const unsigned short* __restrict__ w2f,
    float* __restrict__ out) {
  __shared__ __align__(16) char smem[24576];
  const int t = threadIdx.x;
  const int l = t & 63;
  const int w = t >> 6;        // wave id
  const int lr = l & 15;
  const int lq = l >> 4;
  const long n0 = (long)blockIdx.x * TILE;

  // ---- P0: c[r][f] = sum_d x[r][d][f]^2, fp32 from un-rounded x -> bf16 LDS.
  // Thread t: row r = t>>3, features f0..f0+15 (f0 = (t&7)*16). Coalesced.
  {
    const int r = t >> 3;
    const int f0 = (t & 7) * 16;
    const float* xp = x + (n0 + r) * 384 + f0;
    float4 xa[12];
#pragma unroll
    for (int d = 0; d < 3; ++d)
#pragma unroll
      for (int i = 0; i < 4; ++i)
        xa[d * 4 + i] = *(const float4*)(xp + d * 128 + 4 * i);
    unsigned cpk[8];
#pragma unroll
    for (int i = 0; i < 4; ++i) {
      float4 a = xa[i], b = xa[4 + i], c = xa[8 + i];
      float c0 = a.x * a.x + b.x * b.x + c.x * c.x;
      float c1 = a.y * a.y + b.y * b.y + c.y * c.y;
      float c2 = a.z * a.z + b.z * b.z + c.z * c.z;
      float c3 = a.w * a.w + b.w * b.w + c.w * c.w;
      cpk[2 * i]     = pk2(c0, c1);
      cpk[2 * i + 1] = pk2(c2, c3);
    }
    uint4 w0 = { cpk[0], cpk[1], cpk[2], cpk[3] };
    uint4 w1 = { cpk[4], cpk[5], cpk[6], cpk[7] };
    *(uint4*)(smem + SW(r * 256 + f0 * 2))      = w0;
    *(uint4*)(smem + SW(r * 256 + f0 * 2 + 16)) = w1;
  }
  __syncthreads();   // (1) c visible

  // ---- MLP, K-chunked (128 mids/chunk), h1 double-buffered @8192/@16384.
  f32x4 acc3[2][2] = {};
#pragma unroll
  for (int ch = 0; ch < 4; ++ch) {
    // GEMM2 chunk: h1c = tanh(c @ W1[:,chunk] + b1) ; reads c only
    f32x4 acc2[2][2] = {};
#pragma unroll
    for (int kt = 0; kt < 4; ++kt) {
      bf16x8 a2[2];
#pragma unroll
      for (int mt = 0; mt < 2; ++mt)
        a2[mt] = *(const bf16x8*)(smem + SW((mt * 16 + lr) * 256 + kt * 64 + lq * 16));
#pragma unroll
      for (int jj = 0; jj < 2; ++jj) {
        bf16x8 b = *(const bf16x8*)(w1f + (size_t)((kt * 32 + ch * 8 + 2 * w + jj) * 64 + l) * 8);
#pragma unroll
        for (int mt = 0; mt < 2; ++mt) acc2[mt][jj] = mfma16(a2[mt], b, acc2[mt][jj]);
      }
    }
    // epilogue: bias + tanh -> packed b32 into buf[ch&1]
    // (safe pre-barrier: other waves only read the OTHER buffer now)
    const int bufb = 8192 + (ch & 1) * 8192;
    float2 b1v = *(const float2*)(b1 + ch * 128 + w * 32 + 2 * lr);
#pragma unroll
    for (int mt = 0; mt < 2; ++mt)
#pragma unroll
      for (int reg = 0; reg < 4; ++reg) {
        int row = mt * 16 + 4 * lq + reg;
        unsigned pk = pk2(fast_tanh(acc2[mt][0][reg] + b1v.x),
                          fast_tanh(acc2[mt][1][reg] + b1v.y));
        *(unsigned*)(smem + SW(bufb + row * 256 + w * 64 + 4 * lr)) = pk;
      }
    __syncthreads();   // (2..5) h1 chunk visible
    // GEMM3 partial: acc3 += h1c @ W2[K-slice,:]
#pragma unroll
    for (int kt = 0; kt < 4; ++kt) {
      bf16x8 a3[2];
#pragma unroll
      for (int mt = 0; mt < 2; ++mt)
        a3[mt] = *(const bf16x8*)(smem + SW(bufb + (mt * 16 + lr) * 256 + kt * 64 + lq * 16));
#pragma unroll
      for (int jj = 0; jj < 2; ++jj) {
        bf16x8 b = *(const bf16x8*)(w2f + (size_t)(((ch * 4 + kt) * 8 + 2 * w + jj) * 64 + l) * 8);
#pragma unroll
        for (int mt = 0; mt < 2; ++mt) acc3[mt][jj] = mfma16(a3[mt], b, acc3[mt][jj]);
      }
    }
  }

  // ---- h2 = acc3 + b2 -> bf16 pairs into buf0 (@8192).
  // Safe: last buf0 readers (ch2's GEMM3) all precede barrier (5).
  {
    float2 b2v = *(const float2*)(b2 + w * 32 + 2 * lr);
#pragma unroll
    for (int mt = 0; mt < 2; ++mt)
#pragma unroll
      for (int reg = 0; reg < 4; ++reg) {
        int row = mt * 16 + 4 * lq + reg;
        *(unsigned*)(smem + SW(8192 + row * 256 + w * 64 + 4 * lr)) =
            pk2(acc3[mt][0][reg] + b2v.x, acc3[mt][1][reg] + b2v.y);
      }
  }
  __syncthreads();   // (6) h2 visible

  // ---- GEMM1 + fused epilogue: linx = x @ Wp (A-frags direct from global x,
  // L3-hot re-read), out = linx * h2 immediately. No persistent accumulators.
  {
    // B-fragments for this wave's col pair, resident (8 x 16B from L2 ws)
    bf16x8 bp[4][2];
#pragma unroll
    for (int kt = 0; kt < 4; ++kt)
#pragma unroll
      for (int jj = 0; jj < 2; ++jj)
        bp[kt][jj] = *(const bf16x8*)(wpf + (size_t)((kt * 8 + 2 * w + jj) * 64 + l) * 8);

#pragma unroll 2
    for (int mt = 0; mt < 6; ++mt) {
      const float* xr = x + (n0 * 3 + mt * 16 + lr) * 128;
      f32x4 acc[2] = {};
#pragma unroll
      for (int kt = 0; kt < 4; ++kt) {
        float4 u0 = *(const float4*)(xr + kt * 32 + lq * 8);
        float4 u1 = *(const float4*)(xr + kt * 32 + lq * 8 + 4);
        bf16x8 a = cvt8(u0, u1);
        acc[0] = mfma16(a, bp[kt][0], acc[0]);
        acc[1] = mfma16(a, bp[kt][1], acc[1]);
      }
#pragma unroll
      for (int reg = 0; reg < 4; ++reg) {
        int rp = mt * 16 + 4 * lq + reg;
        int n = rp / 3;   // magic-mul
        unsigned hp = *(const unsigned*)(smem + SW(8192 + n * 256 + w * 64 + 4 * lr));
        float2 o = { acc[0][reg] * bflo(hp), acc[1][reg] * bfhi(hp) };
        *(float2*)(out + n0 * 384 + (long)rp * 128 + w * 32 + 2 * lr) = o;
      }
    }
  }
}

extern "C" void kernel_launch(void* const* d_in, const int* in_sizes, int n_in,
                              void* d_out, int out_size, void* d_ws, size_t ws_size,
                              hipStream_t stream) {
  const float* x  = (const float*)d_in[0];
  const float* Wp = (const float*)d_in[1];
  const float* W1 = (const float*)d_in[2];
  const float* b1 = (const float*)d_in[3];
  const float* W2 = (const float*)d_in[4];
  const float* b2 = (const float*)d_in[5];
  float* out = (float*)d_out;

  // ws layout: W1f [128KB] | W2f [128KB] | Wpf [32KB]
  if (ws_size < 294912) return;
  unsigned short* w1f = (unsigned short*)d_ws;
  unsigned short* w2f = (unsigned short*)((char*)d_ws + 131072);
  unsigned short* wpf = (unsigned short*)((char*)d_ws + 262144);

  prep_weights<<<72, 256, 0, stream>>>(Wp, W1, W2, wpf, w1f, w2f);
  fused_kernel<<<NBLOCKS, 256, 0, stream>>>(x, b1, b2, wpf, w1f, w2f, out);
}

// Round 6
// 209.159 us; speedup vs baseline: 1.3793x; 1.3721x over previous
//
#include <hip/hip_runtime.h>
#include <hip/hip_bf16.h>

// Problem constants
#define NROWS   200000
#define TILE    32                  // rows (n) per block
#define NBLOCKS (NROWS / TILE)      // 6250, exact

typedef __attribute__((ext_vector_type(4))) float f32x4;
typedef __attribute__((ext_vector_type(8))) short bf16x8;

// fp32 pair -> packed bf16x2 (RNE), compiler-lowered packed convert
__device__ __forceinline__ unsigned pk2(float lo, float hi) {
  float2 f{lo, hi};
  __hip_bfloat162 h = __float22bfloat162_rn(f);
  unsigned u;
  __builtin_memcpy(&u, &h, 4);
  return u;
}
// scalar fp32 -> bf16 bits (RNE) — weight prep only (runs once)
__device__ __forceinline__ unsigned short f2bf(float f) {
  unsigned b = __float_as_uint(f);
  b += 0x7fffu + ((b >> 16) & 1u);
  return (unsigned short)(b >> 16);
}
__device__ __forceinline__ float bflo(unsigned pk) { return __uint_as_float(pk << 16); }
__device__ __forceinline__ float bfhi(unsigned pk) { return __uint_as_float(pk & 0xffff0000u); }
__device__ __forceinline__ f32x4 mfma16(bf16x8 a, bf16x8 b, f32x4 c) {
  return __builtin_amdgcn_mfma_f32_16x16x32_bf16(a, b, c, 0, 0, 0);
}
__device__ __forceinline__ float fast_tanh(float x) {
  float e = __expf(2.0f * x);
  return 1.0f - __fdividef(2.0f, e + 1.0f);
}
// LDS XOR swizzle on byte offsets (uniform 256B row pitch, row = byte>>8):
// flips bits 4..6 with row&7; pure function of the offset -> consistent;
// preserves 16B alignment; <=2-way bank aliasing on all access patterns here.
__device__ __forceinline__ int SW(int b) { return b ^ (((b >> 8) & 7) << 4); }

// ---------------------------------------------------------------------------
// Weight prep: W[K][Nout] fp32 -> bf16 MFMA-B fragments with INTERLEAVED
// column mapping: fragment (kt,nt), lane l, elem i <-
//     W[kt*32 + 8*(l>>4) + i][(nt>>1)*32 + 2*(l&15) + (nt&1)]
// Wave w owns tiles {2w,2w+1} -> a lane's two D-cols are adjacent features
// 32w+2*lr{,+1} -> packed b32 LDS writes / float2 global stores downstream.
// ---------------------------------------------------------------------------
__global__ void prep_weights(const float* __restrict__ Wp,
                             const float* __restrict__ W1,
                             const float* __restrict__ W2,
                             unsigned short* __restrict__ wpf,
                             unsigned short* __restrict__ w1f,
                             unsigned short* __restrict__ w2f) {
  int t = blockIdx.x * 256 + threadIdx.x;   // 72*256 = 18432 = 288*64
  int q = t >> 6, l = t & 63;
  const float* W; unsigned short* dst; int NT, Nout, qb;
  if (q < 32)       { W = Wp; dst = wpf; NT = 8;  Nout = 128; qb = q; }
  else if (q < 160) { W = W1; dst = w1f; NT = 32; Nout = 512; qb = q - 32; }
  else              { W = W2; dst = w2f; NT = 8;  Nout = 128; qb = q - 160; }
  int kt = qb / NT, nt = qb % NT;
  int row0 = kt * 32 + 8 * (l >> 4);
  int col  = (nt >> 1) * 32 + 2 * (l & 15) + (nt & 1);   // interleaved
  unsigned short v[8];
#pragma unroll
  for (int i = 0; i < 8; ++i) v[i] = f2bf(W[(row0 + i) * Nout + col]);
  uint4 pack;
  pack.x = (unsigned)v[0] | ((unsigned)v[1] << 16);
  pack.y = (unsigned)v[2] | ((unsigned)v[3] << 16);
  pack.z = (unsigned)v[4] | ((unsigned)v[5] << 16);
  pack.w = (unsigned)v[6] | ((unsigned)v[7] << 16);
  *(uint4*)(dst + (size_t)(qb * 64 + l) * 8) = pack;
}

// ---------------------------------------------------------------------------
// Fused kernel (R6 = R3 structure + packed converts + c-frag hoist +
// GEMM2 software-pipelined across the chunk barrier).
// 32 rows / 256 threads (4 waves). LDS = 32768 B, SW-swizzled, 256B pitch:
//   [0,24576): x bf16 [96 rows'=3n+d][128]    (dead after GEMM1)
//     overlay: h1 buf0 @0 | h1 buf1 @8192 | h2 @16384
//   [24576,32768): c bf16 [32][128]           (never overwritten)
// Phase order: P0 | GEMM1 (lx packed to bf16 regs) | MLP chunks pipelined:
//   GEMM2(0); bar; { epi(ch); GEMM2(ch+1); bar; GEMM3(ch) }x4 | h2 | bar | out
// launch_bounds(256,2): R2/R4 showed tighter bounds spill (+50MB traffic).
// ---------------------------------------------------------------------------
__global__ __launch_bounds__(256, 2) void fused_kernel(
    const float* __restrict__ x,
    const float* __restrict__ b1,
    const float* __restrict__ b2,
    const unsigned short* __restrict__ wpf,
    const unsigned short* __restrict__ w1f,
    const unsigned short* __restrict__ w2f,
    float* __restrict__ out) {
  __shared__ __align__(16) char smem[32768];
  const int t = threadIdx.x;
  const int l = t & 63;
  const int w = t >> 6;        // wave id (uniform per wave)
  const int lr = l & 15;
  const int lq = l >> 4;
  const long n0 = (long)blockIdx.x * TILE;

  // ---- P0: stage x -> bf16 LDS; c = sum_d x^2 in fp32 from un-rounded x.
  {
    float4 v[4][3];
#pragma unroll
    for (int k = 0; k < 4; ++k) {
      int p = t + k * 256, r = p >> 5, f = (p & 31) * 4;
      const float* xp = x + (n0 + r) * 384 + f;
      v[k][0] = *(const float4*)(xp);
      v[k][1] = *(const float4*)(xp + 128);
      v[k][2] = *(const float4*)(xp + 256);
    }
#pragma unroll
    for (int k = 0; k < 4; ++k) {
      int p = t + k * 256, r = p >> 5, f = (p & 31) * 4;
      float4 a = v[k][0], b = v[k][1], c = v[k][2];
      uint2 s0 = { pk2(a.x, a.y), pk2(a.z, a.w) };
      uint2 s1 = { pk2(b.x, b.y), pk2(b.z, b.w) };
      uint2 s2 = { pk2(c.x, c.y), pk2(c.z, c.w) };
      uint2 sc = { pk2(a.x*a.x + b.x*b.x + c.x*c.x,
                       a.y*a.y + b.y*b.y + c.y*c.y),
                   pk2(a.z*a.z + b.z*b.z + c.z*c.z,
                       a.w*a.w + b.w*b.w + c.w*c.w) };
      *(uint2*)(smem + SW((3 * r + 0) * 256 + f * 2)) = s0;
      *(uint2*)(smem + SW((3 * r + 1) * 256 + f * 2)) = s1;
      *(uint2*)(smem + SW((3 * r + 2) * 256 + f * 2)) = s2;
      *(uint2*)(smem + SW(24576 + r * 256 + f * 2))   = sc;
    }
  }
  __syncthreads();   // (1) x + c visible

  // ---- GEMM1: linx[r'][g], 96x128. Wave w owns interleaved cols
  // {32w+2*lr, 32w+2*lr+1} via tiles {2w,2w+1}. Packed to bf16 pairs.
  unsigned lx[6][4];
  {
    f32x4 acc1[6][2] = {};
#pragma unroll
    for (int kt = 0; kt < 4; ++kt) {
      bf16x8 a[6];
#pragma unroll
      for (int mt = 0; mt < 6; ++mt)
        a[mt] = *(const bf16x8*)(smem + SW((mt * 16 + lr) * 256 + kt * 64 + lq * 16));
#pragma unroll
      for (int jj = 0; jj < 2; ++jj) {
        bf16x8 b = *(const bf16x8*)(wpf + (size_t)((kt * 8 + 2 * w + jj) * 64 + l) * 8);
#pragma unroll
        for (int mt = 0; mt < 6; ++mt) acc1[mt][jj] = mfma16(a[mt], b, acc1[mt][jj]);
      }
    }
#pragma unroll
    for (int mt = 0; mt < 6; ++mt)
#pragma unroll
      for (int reg = 0; reg < 4; ++reg)
        lx[mt][reg] = pk2(acc1[mt][0][reg], acc1[mt][1][reg]);
  }

  // ---- c A-fragments hoisted to registers (identical for every chunk)
  bf16x8 cfrag[4][2];
#pragma unroll
  for (int kt = 0; kt < 4; ++kt)
#pragma unroll
    for (int mt = 0; mt < 2; ++mt)
      cfrag[kt][mt] = *(const bf16x8*)(smem + SW(24576 + (mt * 16 + lr) * 256 + kt * 64 + lq * 16));

  // ---- MLP, K-chunked (128 mids/chunk), h1 dbuf @0/@8192, GEMM2 pipelined.
  f32x4 acc2[2][2];
  auto do_gemm2 = [&](int ch) {   // no LDS access: cfrag regs + global weights
#pragma unroll
    for (int mt = 0; mt < 2; ++mt)
#pragma unroll
      for (int jj = 0; jj < 2; ++jj) { f32x4 z = {}; acc2[mt][jj] = z; }
#pragma unroll
    for (int kt = 0; kt < 4; ++kt)
#pragma unroll
      for (int jj = 0; jj < 2; ++jj) {
        bf16x8 b = *(const bf16x8*)(w1f + (size_t)((kt * 32 + ch * 8 + 2 * w + jj) * 64 + l) * 8);
#pragma unroll
        for (int mt = 0; mt < 2; ++mt) acc2[mt][jj] = mfma16(cfrag[kt][mt], b, acc2[mt][jj]);
      }
  };

  f32x4 acc3[2][2] = {};
  do_gemm2(0);
  __syncthreads();   // (2) GEMM1's x reads done; buf0 (aliases x) now writable

#pragma unroll
  for (int ch = 0; ch < 4; ++ch) {
    // epilogue(ch): bias + tanh -> packed b32 into buf[ch&1]
    {
      const int bufb = (ch & 1) * 8192;
      float2 b1v = *(const float2*)(b1 + ch * 128 + w * 32 + 2 * lr);
#pragma unroll
      for (int mt = 0; mt < 2; ++mt)
#pragma unroll
        for (int reg = 0; reg < 4; ++reg) {
          int row = mt * 16 + 4 * lq + reg;
          unsigned pk = pk2(fast_tanh(acc2[mt][0][reg] + b1v.x),
                            fast_tanh(acc2[mt][1][reg] + b1v.y));
          *(unsigned*)(smem + SW(bufb + row * 256 + w * 64 + 4 * lr)) = pk;
        }
    }
    // GEMM2(ch+1) overlaps the barrier below (touches no LDS)
    if (ch < 3) do_gemm2(ch + 1);
    __syncthreads();   // (3..6) h1 chunk visible
    // GEMM3 partial: acc3 += h1c @ W2[K-slice,:]
    {
      const int bufb = (ch & 1) * 8192;
#pragma unroll
      for (int kt = 0; kt < 4; ++kt) {
        bf16x8 a3[2];
#pragma unroll
        for (int mt = 0; mt < 2; ++mt)
          a3[mt] = *(const bf16x8*)(smem + SW(bufb + (mt * 16 + lr) * 256 + kt * 64 + lq * 16));
#pragma unroll
        for (int jj = 0; jj < 2; ++jj) {
          bf16x8 b = *(const bf16x8*)(w2f + (size_t)(((ch * 4 + kt) * 8 + 2 * w + jj) * 64 + l) * 8);
#pragma unroll
          for (int mt = 0; mt < 2; ++mt) acc3[mt][jj] = mfma16(a3[mt], b, acc3[mt][jj]);
        }
      }
    }
  }

  // ---- h2 = acc3 + b2 -> bf16 pairs @16384 (x rows 64..95: long dead)
  {
    float2 b2v = *(const float2*)(b2 + w * 32 + 2 * lr);
#pragma unroll
    for (int mt = 0; mt < 2; ++mt)
#pragma unroll
      for (int reg = 0; reg < 4; ++reg) {
        int row = mt * 16 + 4 * lq + reg;
        *(unsigned*)(smem + SW(16384 + row * 256 + w * 64 + 4 * lr)) =
            pk2(acc3[mt][0][reg] + b2v.x, acc3[mt][1][reg] + b2v.y);
      }
  }
  __syncthreads();   // (7) h2 visible

  // ---- Final: out[n,d,g] = linx * h2, float2 stores (128B segments/quad)
#pragma unroll
  for (int mt = 0; mt < 6; ++mt)
#pragma unroll
    for (int reg = 0; reg < 4; ++reg) {
      int rp = mt * 16 + 4 * lq + reg;
      int n = rp / 3;   // magic-mul
      unsigned hp = *(const unsigned*)(smem + SW(16384 + n * 256 + w * 64 + 4 * lr));
      unsigned pk = lx[mt][reg];
      float2 o = { bflo(pk) * bflo(hp), bfhi(pk) * bfhi(hp) };
      *(float2*)(out + n0 * 384 + (long)rp * 128 + w * 32 + 2 * lr) = o;
    }
}

extern "C" void kernel_launch(void* const* d_in, const int* in_sizes, int n_in,
                              void* d_out, int out_size, void* d_ws, size_t ws_size,
                              hipStream_t stream) {
  const float* x  = (const float*)d_in[0];
  const float* Wp = (const float*)d_in[1];
  const float* W1 = (const float*)d_in[2];
  const float* b1 = (const float*)d_in[3];
  const float* W2 = (const float*)d_in[4];
  const float* b2 = (const float*)d_in[5];
  float* out = (float*)d_out;

  // ws layout: W1f [128KB] | W2f [128KB] | Wpf [32KB]
  if (ws_size < 294912) return;
  unsigned short* w1f = (unsigned short*)d_ws;
  unsigned short* w2f = (unsigned short*)((char*)d_ws + 131072);
  unsigned short* wpf = (unsigned short*)((char*)d_ws + 262144);

  prep_weights<<<72, 256, 0, stream>>>(Wp, W1, W2, wpf, w1f, w2f);
  fused_kernel<<<NBLOCKS, 256, 0, stream>>>(x, b1, b2, wpf, w1f, w2f, out);
}